// Round 14
// baseline (146.000 us; speedup 1.0000x reference)
//
#include <hip/hip_runtime.h>
#include <cstdint>
#include <cstddef>

typedef __attribute__((ext_vector_type(8))) short short8;
typedef __attribute__((ext_vector_type(4))) float f32x4;

constexpr int Bn = 64, Tn = 1024, Hn = 256, Kn = 4;
constexpr int TT = 128;           // T-rows per block
constexpr int AROWS = TT + 2;     // 130 staged x-rows (t0-1 .. t0+128)
constexpr int ARSTR = 144;        // A-LDS row stride bytes (hi 64B + lo 64B + 16 pad)
constexpr int ABUFSZ = AROWS * ARSTR;   // 18,720 B per buffer

// round-to-nearest-even fp32 -> bf16 bits
__device__ __forceinline__ unsigned bf16rne(float f) {
  unsigned u = __float_as_uint(f);
  return (u + 0x7fffu + ((u >> 16) & 1u)) >> 16;
}

// Pack conv_w into MFMA-B-fragment-ready hi/lo bf16:
// Bp[fid(24 ks x 2 p x 16 nf)][lane(64)][j(8)], value = part_p(conv_w[n][i][dt])
// where k = ks*32 + (lane>>4)*8 + j (dt=k>>8, i=k&255), n = nf*16 + (lane&15).
__global__ __launch_bounds__(256) void pack_b_k(const float* __restrict__ conv_w,
                                                unsigned short* __restrict__ Bp) {
  int gt = blockIdx.x * 256 + threadIdx.x;   // 0..49151
  int fid = gt >> 6, l = gt & 63;
  int ks = fid >> 5, rem = fid & 31;
  int p = rem >> 4, nf = rem & 15;
  int n = nf * 16 + (l & 15);
  int k0 = ks * 32 + ((l >> 4) << 3);
  short8 s;
  #pragma unroll
  for (int j = 0; j < 8; ++j) {
    int k = k0 + j;
    int dt = k >> 8, i = k & 255;
    float w = conv_w[n * 768 + i * 3 + dt];
    unsigned hb = bf16rne(w);
    if (p == 0) s[j] = (short)hb;
    else        s[j] = (short)bf16rne(w - __uint_as_float(hb << 16));
  }
  *reinterpret_cast<short8*>(Bp + (size_t)fid * 512 + l * 8) = s;
}

// lgkm-only barrier: ds_writes visible, global VGPR loads keep flying
// (avoids __syncthreads()'s vmcnt(0) drain). Uniform control flow only.
#define GBAR() asm volatile("s_waitcnt lgkmcnt(0)\n\ts_barrier" ::: "memory")

// Fused conv1d(k=3,pad=1)+bias+ReLU+Linear(256->4) via bf16 3-way-split MFMA
// (AhBh + AlBh + AhBl; dropped AlBl <= 2^-18 relative).
// Block: 128(T) x 128(N), 4 waves (64x64 each = 4x4 16x16 frags).
// A: hi/lo bf16, double-buffered LDS (2 x 18,720 B), 8 groups of 32 chans.
// B: Bh double-set VGPR prefetch across STEPs; Bl SINGLE-set, loaded at
//    STEP top and consumed in a 3rd MFMA phase (~620 cyc later, L2 covered)
//    -> arch VGPR ~104, +64 acc = 168 -> 3 waves/SIMD (3 blocks/CU).
// Per-acc FP order unchanged: +AhBh, +AlBh, +AhBl per K-step.
__global__ __launch_bounds__(256, 3) void emis_k(const float* __restrict__ x,
    const unsigned short* __restrict__ Bp, const float* __restrict__ conv_b,
    const float* __restrict__ lin_w, float* __restrict__ em2) {
  __shared__ __align__(16) char A_lds[2 * ABUFSZ];   // 37,440 B

  const int b = blockIdx.z, ny = blockIdx.y, t0 = blockIdx.x * TT;
  const int tid = threadIdx.x, lane = tid & 63, w = tid >> 6;
  const int wm = w >> 1, wn = w & 1;
  const float* xb = x + (size_t)b * Tn * Hn;

  float4 pre[5];                    // A-prefetch regs (20 VGPR)

  // issue group ig's global loads (no LDS touch)
  auto loadA = [&](int ig) {
    #pragma unroll
    for (int it = 0; it < 5; ++it) {
      int idx = it * 256 + tid;
      if (idx < AROWS * 8) {
        int row = idx >> 3, c4 = idx & 7;
        int trow = t0 - 1 + row;
        float4 v = make_float4(0.f, 0.f, 0.f, 0.f);
        if (trow >= 0 && trow < Tn)
          v = *reinterpret_cast<const float4*>(xb + (size_t)trow * Hn + ig * 32 + c4 * 4);
        pre[it] = v;
      }
    }
  };
  // convert + write pre[] into buffer at byte offset BOFF
  auto writeA = [&](int boff) {
    #pragma unroll
    for (int it = 0; it < 5; ++it) {
      int idx = it * 256 + tid;
      if (idx < AROWS * 8) {
        int row = idx >> 3, c4 = idx & 7;
        float vf[4] = {pre[it].x, pre[it].y, pre[it].z, pre[it].w};
        unsigned h[4], lo[4];
        #pragma unroll
        for (int q = 0; q < 4; ++q) {
          h[q] = bf16rne(vf[q]);
          lo[q] = bf16rne(vf[q] - __uint_as_float(h[q] << 16));
        }
        uint2 hp, lp;
        hp.x = h[0] | (h[1] << 16);  hp.y = h[2] | (h[3] << 16);
        lp.x = lo[0] | (lo[1] << 16); lp.y = lo[2] | (lo[3] << 16);
        char* base = A_lds + boff + row * ARSTR + c4 * 8;
        *reinterpret_cast<uint2*>(base) = hp;        // hi plane
        *reinterpret_cast<uint2*>(base + 64) = lp;   // lo plane
      }
    }
  };

  // B-fragment source base for this wave (4 nf frags per set)
  const char* bsrc = reinterpret_cast<const char*>(Bp)
      + (size_t)(ny * 8 + wn * 4) * 1024 + lane * 16;
  auto loadB4 = [&](short8* Bv, int ks, int p) {
    #pragma unroll
    for (int nf = 0; nf < 4; ++nf)
      Bv[nf] = *reinterpret_cast<const short8*>(
          bsrc + (size_t)((ks * 2 + p) * 16 + nf) * 1024);
  };

  f32x4 acc[4][4];
  #pragma unroll
  for (int mf = 0; mf < 4; ++mf)
    #pragma unroll
    for (int nf = 0; nf < 4; ++nf) acc[mf][nf] = (f32x4)0.f;

  // per-lane A base: row=(lane&15), k-chans=(lane>>4)*8 (16B), +wm 64-row block
  const char* aB = A_lds + (lane & 15) * ARSTR + ((lane >> 4) << 4) + wm * 64 * ARSTR;

  short8 BhA[4], BhB[4], Bl[4];

// one K-step in buffer ABUF: consume BH (prefetched) + Bl (loaded here,
// used in phase 2); prefetch next Bh set into NBH.
#define STEP(ABUF, DT, BH, NBH, KSC, KSN)                                     \
  {                                                                           \
    loadB4(Bl, (KSC), 1);                                                     \
    loadB4(NBH, (KSN), 0);                                                    \
    __builtin_amdgcn_s_setprio(1);                                            \
    _Pragma("unroll")                                                         \
    for (int mf = 0; mf < 4; ++mf) {                                          \
      const char* ap = aB + (ABUF) + (mf * 16 + (DT)) * ARSTR;                \
      short8 Ah = *reinterpret_cast<const short8*>(ap);                       \
      short8 Al = *reinterpret_cast<const short8*>(ap + 64);                  \
      _Pragma("unroll")                                                       \
      for (int nf = 0; nf < 4; ++nf) {                                        \
        f32x4 c = acc[mf][nf];                                                \
        c = __builtin_amdgcn_mfma_f32_16x16x32_bf16(Ah, BH[nf], c, 0, 0, 0);  \
        c = __builtin_amdgcn_mfma_f32_16x16x32_bf16(Al, BH[nf], c, 0, 0, 0);  \
        acc[mf][nf] = c;                                                      \
      }                                                                       \
    }                                                                         \
    _Pragma("unroll")                                                         \
    for (int mf = 0; mf < 4; ++mf) {                                          \
      const char* ap = aB + (ABUF) + (mf * 16 + (DT)) * ARSTR;                \
      short8 Ah = *reinterpret_cast<const short8*>(ap);                       \
      _Pragma("unroll")                                                       \
      for (int nf = 0; nf < 4; ++nf)                                          \
        acc[mf][nf] = __builtin_amdgcn_mfma_f32_16x16x32_bf16(                \
            Ah, Bl[nf], acc[mf][nf], 0, 0, 0);                                \
    }                                                                         \
    __builtin_amdgcn_s_setprio(0);                                            \
  }

  // prologue: A group 0 -> buf0 (latency exposed once), Bh ks=0 in flight
  loadA(0);
  loadB4(BhA, 0, 0);
  writeA(0);
  GBAR();

  #pragma unroll 1
  for (int igp = 0; igp < 4; ++igp) {
    const int ig0 = igp * 2, ig1 = ig0 + 1;
    // ---- group ig0 in buf0 ----
    loadA(ig1);                                  // issue-early for buf1
    STEP(0, 0, BhA, BhB, ig0,      8 + ig0);
    STEP(0, 1, BhB, BhA, 8 + ig0,  16 + ig0);
    STEP(0, 2, BhA, BhB, 16 + ig0, ig1);
    writeA(ABUFSZ);                              // write-late into buf1
    GBAR();
    // ---- group ig1 in buf1 ----
    if (ig1 < 7) loadA(ig1 + 1);
    STEP(ABUFSZ, 0, BhB, BhA, ig1,      8 + ig1);
    STEP(ABUFSZ, 1, BhA, BhB, 8 + ig1,  16 + ig1);
    STEP(ABUFSZ, 2, BhB, BhA, 16 + ig1, (ig1 < 7 ? ig1 + 1 : 0));
    if (ig1 < 7) writeA(0);
    GBAR();
  }
#undef STEP

  // ---- Epilogue: +conv_b, ReLU, x lin_w^T partials over this wave's cols ----
  // C/D layout: col = lane&15, row = (lane>>4)*4 + v  (m89-verified).
  f32x4 pem[4][4];   // [mf][v] -> 4 kk partial sums
  #pragma unroll
  for (int mf = 0; mf < 4; ++mf)
    #pragma unroll
    for (int v = 0; v < 4; ++v) pem[mf][v] = (f32x4)0.f;

  #pragma unroll
  for (int nf = 0; nf < 4; ++nf) {
    const int gcol = ny * 128 + wn * 64 + nf * 16 + (lane & 15);
    const float cb = conv_b[gcol];
    f32x4 lw;
    lw[0] = lin_w[gcol]; lw[1] = lin_w[256 + gcol];
    lw[2] = lin_w[512 + gcol]; lw[3] = lin_w[768 + gcol];
    #pragma unroll
    for (int mf = 0; mf < 4; ++mf)
      #pragma unroll
      for (int v = 0; v < 4; ++v) {
        float val = fmaxf(acc[mf][nf][v] + cb, 0.f);
        pem[mf][v] += val * lw;
      }
  }
  // reduce over the 16 col-lanes (lane bits 0..3)
  #pragma unroll
  for (int mf = 0; mf < 4; ++mf)
    #pragma unroll
    for (int v = 0; v < 4; ++v) {
      f32x4 t = pem[mf][v];
      #pragma unroll
      for (int m = 1; m < 16; m <<= 1) {
        f32x4 q;
        q[0] = __shfl_xor(t[0], m); q[1] = __shfl_xor(t[1], m);
        q[2] = __shfl_xor(t[2], m); q[3] = __shfl_xor(t[3], m);
        t += q;
      }
      pem[mf][v] = t;
    }
  __syncthreads();                    // all waves done with A_lds (reuse)
  // cross-wave (wn) combine via LDS
  float* red = reinterpret_cast<float*>(A_lds);   // [128 rows][2 wn][4 kk]
  if ((lane & 15) == 0) {
    const int g = lane >> 4;
    #pragma unroll
    for (int mf = 0; mf < 4; ++mf)
      #pragma unroll
      for (int v = 0; v < 4; ++v) {
        int r = wm * 64 + mf * 16 + g * 4 + v;
        *reinterpret_cast<f32x4*>(red + (r * 2 + wn) * 4) = pem[mf][v];
      }
  }
  __syncthreads();
  if (tid < 128) {
    f32x4 s0 = *reinterpret_cast<f32x4*>(red + tid * 8);
    f32x4 s1 = *reinterpret_cast<f32x4*>(red + tid * 8 + 4);
    f32x4 s = s0 + s1;
    *reinterpret_cast<f32x4*>(em2 + ((size_t)(b * Tn + t0 + tid) * 2 + ny) * 4) = s;
  }
}

// byte-map composition c(k) = a(b(k))
__device__ __forceinline__ unsigned int compose_map(unsigned int a, unsigned int b) {
#if __has_builtin(__builtin_amdgcn_perm)
  return __builtin_amdgcn_perm(a, a, b);
#else
  unsigned int c = 0;
  #pragma unroll
  for (int k = 0; k < 4; ++k) {
    unsigned int sel = (b >> (8 * k)) & 0xffu;
    c |= ((a >> (8 * sel)) & 0xffu) << (8 * k);
  }
  return c;
#endif
}

// quad_perm broadcast of lane J (within each 4-lane quad) via DPP
template <int J>
__device__ __forceinline__ float qb(float v) {
  return __int_as_float(__builtin_amdgcn_update_dpp(
      0, __float_as_int(v), (J * 0x55), 0xf, 0xf, true));
}

// One quad-parallel Viterbi step for lane k (values bitwise = scalar form).
#define PSTEP(EV, T)                                                       \
  {                                                                        \
    shf[((T) - 1) * 4 + kk] = s;                                           \
    float c0 = qb<0>(s) + trc0;                                            \
    float c1 = qb<1>(s) + trc1;                                            \
    float c2 = qb<2>(s) + trc2;                                            \
    float c3 = qb<3>(s) + trc3;                                            \
    s = fmaxf(fmaxf(c0, c1), fmaxf(c2, c3)) + (EV);                        \
  }

// CRF Viterbi decode. Stage: se[t] = em2[t][half0] + em2[t][half1] + lin_b.
// Forward: 4-lane quad-parallel scan. Backtrace: 64 lanes rebuild argmax
// maps, v_perm suffix-scan (integer-exact).
__global__ __launch_bounds__(64) void viterbi_k(const float* __restrict__ em2,
    const float* __restrict__ lin_b, const float* __restrict__ cstart,
    const float* __restrict__ cend, const float* __restrict__ ctrans,
    int* __restrict__ out) {
  __shared__ float4 se[Tn];          // emissions, 16 KB
  __shared__ float4 sh[Tn - 1];      // score vector BEFORE step t+1, 16 KB
  __shared__ int s_last;
  const int b = blockIdx.x, lane = threadIdx.x;
  const float4* e2 = reinterpret_cast<const float4*>(em2 + (size_t)b * Tn * 8);
  const float lb0 = lin_b[0], lb1 = lin_b[1], lb2 = lin_b[2], lb3 = lin_b[3];
  for (int i = lane; i < Tn; i += 64) {
    float4 a = e2[i * 2], c = e2[i * 2 + 1];
    se[i] = make_float4(a.x + c.x + lb0, a.y + c.y + lb1,
                        a.z + c.z + lb2, a.w + c.w + lb3);
  }
  float tr[4][4];
  #pragma unroll
  for (int j = 0; j < 4; ++j)
    #pragma unroll
    for (int k = 0; k < 4; ++k) tr[j][k] = ctrans[j * 4 + k];
  __syncthreads();

  if (lane < 4) {
    const int kk = lane;
    const float* sef = reinterpret_cast<const float*>(se);
    float* shf = reinterpret_cast<float*>(sh);
    const float trc0 = ctrans[0 * 4 + kk];
    const float trc1 = ctrans[1 * 4 + kk];
    const float trc2 = ctrans[2 * 4 + kk];
    const float trc3 = ctrans[3 * 4 + kk];
    float s = cstart[kk] + sef[kk];
    float e[8];
    #pragma unroll
    for (int d = 0; d < 8; ++d) e[d] = sef[(1 + d) * 4 + kk];
    int t = 1;
    #pragma unroll 1
    for (int g = 0; g < 127; ++g, t += 8) {   // t = 1..1016
      float f[8];
      #pragma unroll
      for (int d = 0; d < 8; ++d) f[d] = e[d];
      #pragma unroll
      for (int d = 0; d < 8; ++d) e[d] = sef[(t + 8 + d) * 4 + kk];
      PSTEP(f[0], t);     PSTEP(f[1], t + 1);
      PSTEP(f[2], t + 2); PSTEP(f[3], t + 3);
      PSTEP(f[4], t + 4); PSTEP(f[5], t + 5);
      PSTEP(f[6], t + 6); PSTEP(f[7], t + 7);
    }
    PSTEP(e[0], 1017); PSTEP(e[1], 1018); PSTEP(e[2], 1019);
    PSTEP(e[3], 1020); PSTEP(e[4], 1021); PSTEP(e[5], 1022);
    PSTEP(e[6], 1023);
    s += cend[kk];
    float f0 = __shfl(s, 0), f1 = __shfl(s, 1);
    float f2 = __shfl(s, 2), f3 = __shfl(s, 3);
    if (kk == 0) {
      int tag = 0; float bf = f0;
      if (f1 > bf) { bf = f1; tag = 1; }
      if (f2 > bf) { bf = f2; tag = 2; }
      if (f3 > bf) { bf = f3; tag = 3; }
      s_last = tag;
    }
  }
  __syncthreads();

  const unsigned int ID = 0x03020100u;
  unsigned int mloc[16];
  const int t0 = lane * 16;
  #pragma unroll
  for (int k = 0; k < 16; ++k) {
    const int t = t0 + k;
    if (t < Tn - 1) {
      const float4 s = sh[t];
      const float4 e = se[t + 1];
      const float sj[4] = {s.x, s.y, s.z, s.w};
      const float ev[4] = {e.x, e.y, e.z, e.w};
      unsigned int mw = 0;
      #pragma unroll
      for (int kk = 0; kk < 4; ++kk) {
        float best = (sj[0] + tr[0][kk]) + ev[kk];
        int bi = 0;
        #pragma unroll
        for (int j = 1; j < 4; ++j) {
          float cc = (sj[j] + tr[j][kk]) + ev[kk];
          if (cc > best) { best = cc; bi = j; }
        }
        mw |= (unsigned)bi << (8 * kk);
      }
      mloc[k] = mw;
    } else {
      mloc[k] = ID;
    }
  }
  unsigned int P = mloc[15];
  #pragma unroll
  for (int k = 14; k >= 0; --k) P = compose_map(mloc[k], P);
  #pragma unroll
  for (int d = 1; d < 64; d <<= 1) {
    unsigned int q = (unsigned int)__shfl_down((int)P, d);
    if (lane + d > 63) q = ID;
    P = compose_map(P, q);
  }
  unsigned int E = (unsigned int)__shfl_down((int)P, 1);
  if (lane == 63) E = ID;
  const int last = s_last;
  unsigned int tag = (E >> (8 * last)) & 3u;
  int* ob = out + (size_t)b * Tn;
  #pragma unroll
  for (int k = 15; k >= 0; --k) {
    tag = (mloc[k] >> (8 * tag)) & 3u;
    ob[t0 + k] = (int)tag;
  }
}

extern "C" void kernel_launch(void* const* d_in, const int* in_sizes, int n_in,
                              void* d_out, int out_size, void* d_ws, size_t ws_size,
                              hipStream_t stream) {
  const float* x      = (const float*)d_in[0];
  const float* conv_w = (const float*)d_in[1];
  const float* conv_b = (const float*)d_in[2];
  const float* lin_w  = (const float*)d_in[3];
  const float* lin_b  = (const float*)d_in[4];
  const float* cstart = (const float*)d_in[5];
  const float* cend   = (const float*)d_in[6];
  const float* ctrans = (const float*)d_in[7];
  int* out = (int*)d_out;

  unsigned short* Bp = (unsigned short*)d_ws;              // 786,432 B
  float* em2 = (float*)((char*)d_ws + 786432);             // 2 MB partials

  pack_b_k<<<192, 256, 0, stream>>>(conv_w, Bp);
  emis_k<<<dim3(Tn / TT, 2, Bn), 256, 0, stream>>>(x, Bp, conv_b, lin_w, em2);
  viterbi_k<<<Bn, 64, 0, stream>>>(em2, lin_b, cstart, cend, ctrans, out);
}

// Round 15
// 145.986 us; speedup vs baseline: 1.0001x; 1.0001x over previous
//
#include <hip/hip_runtime.h>
#include <cstdint>
#include <cstddef>

typedef __attribute__((ext_vector_type(8))) short short8;
typedef __attribute__((ext_vector_type(4))) float f32x4;

constexpr int Bn = 64, Tn = 1024, Hn = 256, Kn = 4;
constexpr int TT = 128;            // T-rows per block
constexpr int AROWS = TT + 2;      // 130 staged x-rows
// fallback (v13) layout
constexpr int ARSTR = 144;
constexpr int ABUFSZ = AROWS * ARSTR;        // 18,720 B
// new layout: 128 B/row, XOR-swizzled, no pad
constexpr int ARSTR2 = 128;
constexpr int ABUFSZ2 = AROWS * ARSTR2;      // 16,640 B
constexpr int XROWS = Tn + 2;      // 1026 rows per (b,ig) in xs (halo zero rows)

__device__ __forceinline__ unsigned bf16rne(float f) {
  unsigned u = __float_as_uint(f);
  return (u + 0x7fffu + ((u >> 16) & 1u)) >> 16;
}

// Pack conv_w into MFMA-B-fragment-ready hi/lo bf16 (unchanged, verified).
__global__ __launch_bounds__(256) void pack_b_k(const float* __restrict__ conv_w,
                                                unsigned short* __restrict__ Bp) {
  int gt = blockIdx.x * 256 + threadIdx.x;
  int fid = gt >> 6, l = gt & 63;
  int ks = fid >> 5, rem = fid & 31;
  int p = rem >> 4, nf = rem & 15;
  int n = nf * 16 + (l & 15);
  int k0 = ks * 32 + ((l >> 4) << 3);
  short8 s;
  #pragma unroll
  for (int j = 0; j < 8; ++j) {
    int k = k0 + j;
    int dt = k >> 8, i = k & 255;
    float w = conv_w[n * 768 + i * 3 + dt];
    unsigned hb = bf16rne(w);
    if (p == 0) s[j] = (short)hb;
    else        s[j] = (short)bf16rne(w - __uint_as_float(hb << 16));
  }
  *reinterpret_cast<short8*>(Bp + (size_t)fid * 512 + l * 8) = s;
}

// Pre-split x into the LDS image: xs[(b*8+ig)][trow1 0..1025][kg' 0..7] 16B
// chunks; kg' = kg ^ (trow1&7); kg<4 = hi of chans ig*32+kg*8..+7, kg>=4 = lo.
// Rows trow1=0 (t=-1) and 1025 (t=1024) are zero (conv halo).
__global__ __launch_bounds__(256) void presplit_k(const float* __restrict__ x,
                                                  unsigned char* __restrict__ xs) {
  int idx = blockIdx.x * 256 + threadIdx.x;      // chunk within (b,ig)
  if (idx >= XROWS * 8) return;
  const int bg = blockIdx.y;                     // b*8+ig
  const int kgp = idx & 7, trow1 = idx >> 3;
  const int t = trow1 - 1;
  const int kg = kgp ^ (trow1 & 7);
  unsigned short o[8] = {0, 0, 0, 0, 0, 0, 0, 0};
  if (t >= 0 && t < Tn) {
    const int b = bg >> 3, ig = bg & 7;
    const int c8 = ig * 32 + (kg & 3) * 8;
    const float* src = x + ((size_t)b * Tn + t) * Hn + c8;
    float4 v0 = *reinterpret_cast<const float4*>(src);
    float4 v1 = *reinterpret_cast<const float4*>(src + 4);
    float vf[8] = {v0.x, v0.y, v0.z, v0.w, v1.x, v1.y, v1.z, v1.w};
    if (kg < 4) {
      #pragma unroll
      for (int j = 0; j < 8; ++j) o[j] = (unsigned short)bf16rne(vf[j]);
    } else {
      #pragma unroll
      for (int j = 0; j < 8; ++j) {
        unsigned hb = bf16rne(vf[j]);
        o[j] = (unsigned short)bf16rne(vf[j] - __uint_as_float(hb << 16));
      }
    }
  }
  short8 s;
  #pragma unroll
  for (int j = 0; j < 8; ++j) s[j] = (short)o[j];
  *reinterpret_cast<short8*>(xs + ((size_t)bg * XROWS * 8 + idx) * 16) = s;
}

// async global->LDS, 16B/lane (dest = wave-uniform base + lane*16)
__device__ __forceinline__ void gload_lds16(const void* g, void* l) {
  __builtin_amdgcn_global_load_lds(
      (const __attribute__((address_space(1))) void*)g,
      (__attribute__((address_space(3))) void*)l, 16, 0, 0);
}

// ================= NEW emis: pure-gload A staging =================
// A: pre-split xs staged via global_load_lds (linear dest = swizzled image),
//    double-buffered (2 x 16,640 B). No cvt, no pre[], no ds_write.
// B: Bh/Bl double-set VGPR prefetch (round-13 STEP, bitwise-same math).
// Barriers: counted s_waitcnt vmcnt(8) + s_barrier (B prefetch stays in
// flight; in-order vmcnt retirement guarantees older stage gloads landed).
__global__ __launch_bounds__(256, 3) void emis_k(
    const unsigned char* __restrict__ xs, const unsigned short* __restrict__ Bp,
    const float* __restrict__ conv_b, const float* __restrict__ lin_w,
    float* __restrict__ em2) {
  __shared__ __align__(16) char A_lds[2 * ABUFSZ2];   // 33,280 B

  const int b = blockIdx.z, ny = blockIdx.y, t0 = blockIdx.x * TT;
  const int tid = threadIdx.x, lane = tid & 63, w = tid >> 6;
  const int wm = w >> 1, wn = w & 1;

  // stage group ig into buffer at byte offset boff: 130 rows x 128 B,
  // chunks 0..1039; waves cover 0..1023 (4 instrs), wave 0 adds 976..1039.
  auto stageA = [&](int boff, int ig) {
    const unsigned char* src = xs + ((size_t)(b * 8 + ig) * XROWS + t0) * 128;
    #pragma unroll
    for (int it = 0; it < 4; ++it) {
      const int cbase = (w * 4 + it) * 64;
      gload_lds16(src + (size_t)(cbase + lane) * 16,
                  A_lds + boff + (cbase + lane) * 16);
    }
    if (w == 0)
      gload_lds16(src + (size_t)(976 + lane) * 16,
                  A_lds + boff + (976 + lane) * 16);
  };

  // B-fragment source base for this wave
  const char* bsrc = reinterpret_cast<const char*>(Bp)
      + (size_t)(ny * 8 + wn * 4) * 1024 + lane * 16;
  auto loadB = [&](short8* Bh, short8* Bl, int ks) {
    #pragma unroll
    for (int nf = 0; nf < 4; ++nf) {
      Bh[nf] = *reinterpret_cast<const short8*>(bsrc + (size_t)((ks * 2 + 0) * 16 + nf) * 1024);
      Bl[nf] = *reinterpret_cast<const short8*>(bsrc + (size_t)((ks * 2 + 1) * 16 + nf) * 1024);
    }
  };

  f32x4 acc[4][4];
  #pragma unroll
  for (int mf = 0; mf < 4; ++mf)
    #pragma unroll
    for (int nf = 0; nf < 4; ++nf) acc[mf][nf] = (f32x4)0.f;

  // per-lane A read bases with XOR swizzle: row r = (lane&15)+wm*64+mf*16+dt,
  // chunk kg_h = lane>>4 (hi), kg_l = kg_h+4 (lo); addr = r*128 + (kg^(r&7))*16.
  // r&7 = ((lane&7)+dt)&7. Per-dt bases hold dt*128 + swizzled chunk offset.
  const int l7 = lane & 7, kh = lane >> 4;
  const int Abase = ((lane & 15) + wm * 64) * ARSTR2;
  const char* vAh[3];
  const char* vAl[3];
  #pragma unroll
  for (int dt = 0; dt < 3; ++dt) {
    const int s = (l7 + dt) & 7;
    vAh[dt] = A_lds + Abase + dt * ARSTR2 + ((kh ^ s) << 4);
    vAl[dt] = A_lds + Abase + dt * ARSTR2 + (((kh + 4) ^ s) << 4);
  }

#define BAR8() asm volatile("s_waitcnt vmcnt(8) lgkmcnt(0)\n\ts_barrier" ::: "memory")

#define STEPN(ABUF, DT, BH, BL, NBH, NBL, KSN)                                \
  {                                                                           \
    loadB(NBH, NBL, (KSN));                                                   \
    __builtin_amdgcn_s_setprio(1);                                            \
    _Pragma("unroll")                                                         \
    for (int mf = 0; mf < 4; ++mf) {                                          \
      short8 Ah = *reinterpret_cast<const short8*>(vAh[DT] + (ABUF) + mf * 2048); \
      short8 Al = *reinterpret_cast<const short8*>(vAl[DT] + (ABUF) + mf * 2048); \
      _Pragma("unroll")                                                       \
      for (int nf = 0; nf < 4; ++nf) {                                        \
        f32x4 c = acc[mf][nf];                                                \
        c = __builtin_amdgcn_mfma_f32_16x16x32_bf16(Ah, BH[nf], c, 0, 0, 0);  \
        c = __builtin_amdgcn_mfma_f32_16x16x32_bf16(Al, BH[nf], c, 0, 0, 0);  \
        c = __builtin_amdgcn_mfma_f32_16x16x32_bf16(Ah, BL[nf], c, 0, 0, 0);  \
        acc[mf][nf] = c;                                                      \
      }                                                                       \
    }                                                                         \
    __builtin_amdgcn_s_setprio(0);                                            \
  }

  short8 BhA[4], BlA[4], BhB[4], BlB[4];
  loadB(BhA, BlA, 0);
  stageA(0, 0);
  asm volatile("s_waitcnt vmcnt(0) lgkmcnt(0)\n\ts_barrier" ::: "memory");

  #pragma unroll 1
  for (int igp = 0; igp < 4; ++igp) {
    const int ig0 = igp * 2, ig1 = ig0 + 1;
    // ---- group ig0 in buf0 ----
    stageA(ABUFSZ2, ig1);
    STEPN(0, 0, BhA, BlA, BhB, BlB, 8 + ig0);
    STEPN(0, 1, BhB, BlB, BhA, BlA, 16 + ig0);
    STEPN(0, 2, BhA, BlA, BhB, BlB, ig1);
    BAR8();
    // ---- group ig1 in buf1 ----
    if (ig1 < 7) stageA(0, ig1 + 1);
    STEPN(ABUFSZ2, 0, BhB, BlB, BhA, BlA, 8 + ig1);
    STEPN(ABUFSZ2, 1, BhA, BlA, BhB, BlB, 16 + ig1);
    STEPN(ABUFSZ2, 2, BhB, BlB, BhA, BlA, (ig1 < 7 ? ig1 + 1 : 0));
    BAR8();
  }
#undef STEPN
#undef BAR8

  // ---- Epilogue (unchanged; C/D: col=lane&15, row=(lane>>4)*4+v) ----
  f32x4 pem[4][4];
  #pragma unroll
  for (int mf = 0; mf < 4; ++mf)
    #pragma unroll
    for (int v = 0; v < 4; ++v) pem[mf][v] = (f32x4)0.f;

  #pragma unroll
  for (int nf = 0; nf < 4; ++nf) {
    const int gcol = ny * 128 + wn * 64 + nf * 16 + (lane & 15);
    const float cb = conv_b[gcol];
    f32x4 lw;
    lw[0] = lin_w[gcol]; lw[1] = lin_w[256 + gcol];
    lw[2] = lin_w[512 + gcol]; lw[3] = lin_w[768 + gcol];
    #pragma unroll
    for (int mf = 0; mf < 4; ++mf)
      #pragma unroll
      for (int v = 0; v < 4; ++v) {
        float val = fmaxf(acc[mf][nf][v] + cb, 0.f);
        pem[mf][v] += val * lw;
      }
  }
  #pragma unroll
  for (int mf = 0; mf < 4; ++mf)
    #pragma unroll
    for (int v = 0; v < 4; ++v) {
      f32x4 t = pem[mf][v];
      #pragma unroll
      for (int m = 1; m < 16; m <<= 1) {
        f32x4 q;
        q[0] = __shfl_xor(t[0], m); q[1] = __shfl_xor(t[1], m);
        q[2] = __shfl_xor(t[2], m); q[3] = __shfl_xor(t[3], m);
        t += q;
      }
      pem[mf][v] = t;
    }
  __syncthreads();
  float* red = reinterpret_cast<float*>(A_lds);
  if ((lane & 15) == 0) {
    const int g = lane >> 4;
    #pragma unroll
    for (int mf = 0; mf < 4; ++mf)
      #pragma unroll
      for (int v = 0; v < 4; ++v) {
        int r = wm * 64 + mf * 16 + g * 4 + v;
        *reinterpret_cast<f32x4*>(red + (r * 2 + wn) * 4) = pem[mf][v];
      }
  }
  __syncthreads();
  if (tid < 128) {
    f32x4 s0 = *reinterpret_cast<f32x4*>(red + tid * 8);
    f32x4 s1 = *reinterpret_cast<f32x4*>(red + tid * 8 + 4);
    f32x4 s = s0 + s1;
    *reinterpret_cast<f32x4*>(em2 + ((size_t)(b * Tn + t0 + tid) * 2 + ny) * 4) = s;
  }
}

// ================= FALLBACK emis (round-13 verbatim) =================
#define GBAR() asm volatile("s_waitcnt lgkmcnt(0)\n\ts_barrier" ::: "memory")

__global__ __launch_bounds__(256, 2) void emis_k13(const float* __restrict__ x,
    const unsigned short* __restrict__ Bp, const float* __restrict__ conv_b,
    const float* __restrict__ lin_w, float* __restrict__ em2) {
  __shared__ __align__(16) char A_lds[2 * ABUFSZ];

  const int b = blockIdx.z, ny = blockIdx.y, t0 = blockIdx.x * TT;
  const int tid = threadIdx.x, lane = tid & 63, w = tid >> 6;
  const int wm = w >> 1, wn = w & 1;
  const float* xb = x + (size_t)b * Tn * Hn;

  float4 pre[5];
  auto loadA = [&](int ig) {
    #pragma unroll
    for (int it = 0; it < 5; ++it) {
      int idx = it * 256 + tid;
      if (idx < AROWS * 8) {
        int row = idx >> 3, c4 = idx & 7;
        int trow = t0 - 1 + row;
        float4 v = make_float4(0.f, 0.f, 0.f, 0.f);
        if (trow >= 0 && trow < Tn)
          v = *reinterpret_cast<const float4*>(xb + (size_t)trow * Hn + ig * 32 + c4 * 4);
        pre[it] = v;
      }
    }
  };
  auto writeA = [&](int boff) {
    #pragma unroll
    for (int it = 0; it < 5; ++it) {
      int idx = it * 256 + tid;
      if (idx < AROWS * 8) {
        int row = idx >> 3, c4 = idx & 7;
        float vf[4] = {pre[it].x, pre[it].y, pre[it].z, pre[it].w};
        unsigned h[4], lo[4];
        #pragma unroll
        for (int q = 0; q < 4; ++q) {
          h[q] = bf16rne(vf[q]);
          lo[q] = bf16rne(vf[q] - __uint_as_float(h[q] << 16));
        }
        uint2 hp, lp;
        hp.x = h[0] | (h[1] << 16);  hp.y = h[2] | (h[3] << 16);
        lp.x = lo[0] | (lo[1] << 16); lp.y = lo[2] | (lo[3] << 16);
        char* base = A_lds + boff + row * ARSTR + c4 * 8;
        *reinterpret_cast<uint2*>(base) = hp;
        *reinterpret_cast<uint2*>(base + 64) = lp;
      }
    }
  };

  const char* bsrc = reinterpret_cast<const char*>(Bp)
      + (size_t)(ny * 8 + wn * 4) * 1024 + lane * 16;
  auto loadB = [&](short8* Bh, short8* Bl, int ks) {
    #pragma unroll
    for (int nf = 0; nf < 4; ++nf) {
      Bh[nf] = *reinterpret_cast<const short8*>(bsrc + (size_t)((ks * 2 + 0) * 16 + nf) * 1024);
      Bl[nf] = *reinterpret_cast<const short8*>(bsrc + (size_t)((ks * 2 + 1) * 16 + nf) * 1024);
    }
  };

  f32x4 acc[4][4];
  #pragma unroll
  for (int mf = 0; mf < 4; ++mf)
    #pragma unroll
    for (int nf = 0; nf < 4; ++nf) acc[mf][nf] = (f32x4)0.f;

  const char* aB = A_lds + (lane & 15) * ARSTR + ((lane >> 4) << 4) + wm * 64 * ARSTR;

#define STEP13(ABUF, DT, BH, BL, NBH, NBL, KSN)                               \
  {                                                                           \
    loadB(NBH, NBL, (KSN));                                                   \
    __builtin_amdgcn_s_setprio(1);                                            \
    _Pragma("unroll")                                                         \
    for (int mf = 0; mf < 4; ++mf) {                                          \
      const char* ap = aB + (ABUF) + (mf * 16 + (DT)) * ARSTR;                \
      short8 Ah = *reinterpret_cast<const short8*>(ap);                       \
      short8 Al = *reinterpret_cast<const short8*>(ap + 64);                  \
      _Pragma("unroll")                                                       \
      for (int nf = 0; nf < 4; ++nf) {                                        \
        f32x4 c = acc[mf][nf];                                                \
        c = __builtin_amdgcn_mfma_f32_16x16x32_bf16(Ah, BH[nf], c, 0, 0, 0);  \
        c = __builtin_amdgcn_mfma_f32_16x16x32_bf16(Al, BH[nf], c, 0, 0, 0);  \
        c = __builtin_amdgcn_mfma_f32_16x16x32_bf16(Ah, BL[nf], c, 0, 0, 0);  \
        acc[mf][nf] = c;                                                      \
      }                                                                       \
    }                                                                         \
    __builtin_amdgcn_s_setprio(0);                                            \
  }

  short8 BhA[4], BlA[4], BhB[4], BlB[4];
  loadA(0);
  loadB(BhA, BlA, 0);
  writeA(0);
  GBAR();

  #pragma unroll 1
  for (int igp = 0; igp < 4; ++igp) {
    const int ig0 = igp * 2, ig1 = ig0 + 1;
    loadA(ig1);
    STEP13(0, 0, BhA, BlA, BhB, BlB, 8 + ig0);
    STEP13(0, 1, BhB, BlB, BhA, BlA, 16 + ig0);
    STEP13(0, 2, BhA, BlA, BhB, BlB, ig1);
    writeA(ABUFSZ);
    GBAR();
    if (ig1 < 7) loadA(ig1 + 1);
    STEP13(ABUFSZ, 0, BhB, BlB, BhA, BlA, 8 + ig1);
    STEP13(ABUFSZ, 1, BhA, BlA, BhB, BlB, 16 + ig1);
    STEP13(ABUFSZ, 2, BhB, BlB, BhA, BlA, (ig1 < 7 ? ig1 + 1 : 0));
    if (ig1 < 7) writeA(0);
    GBAR();
  }
#undef STEP13

  f32x4 pem[4][4];
  #pragma unroll
  for (int mf = 0; mf < 4; ++mf)
    #pragma unroll
    for (int v = 0; v < 4; ++v) pem[mf][v] = (f32x4)0.f;

  #pragma unroll
  for (int nf = 0; nf < 4; ++nf) {
    const int gcol = ny * 128 + wn * 64 + nf * 16 + (lane & 15);
    const float cb = conv_b[gcol];
    f32x4 lw;
    lw[0] = lin_w[gcol]; lw[1] = lin_w[256 + gcol];
    lw[2] = lin_w[512 + gcol]; lw[3] = lin_w[768 + gcol];
    #pragma unroll
    for (int mf = 0; mf < 4; ++mf)
      #pragma unroll
      for (int v = 0; v < 4; ++v) {
        float val = fmaxf(acc[mf][nf][v] + cb, 0.f);
        pem[mf][v] += val * lw;
      }
  }
  #pragma unroll
  for (int mf = 0; mf < 4; ++mf)
    #pragma unroll
    for (int v = 0; v < 4; ++v) {
      f32x4 t = pem[mf][v];
      #pragma unroll
      for (int m = 1; m < 16; m <<= 1) {
        f32x4 q;
        q[0] = __shfl_xor(t[0], m); q[1] = __shfl_xor(t[1], m);
        q[2] = __shfl_xor(t[2], m); q[3] = __shfl_xor(t[3], m);
        t += q;
      }
      pem[mf][v] = t;
    }
  __syncthreads();
  float* red = reinterpret_cast<float*>(A_lds);
  if ((lane & 15) == 0) {
    const int g = lane >> 4;
    #pragma unroll
    for (int mf = 0; mf < 4; ++mf)
      #pragma unroll
      for (int v = 0; v < 4; ++v) {
        int r = wm * 64 + mf * 16 + g * 4 + v;
        *reinterpret_cast<f32x4*>(red + (r * 2 + wn) * 4) = pem[mf][v];
      }
  }
  __syncthreads();
  if (tid < 128) {
    f32x4 s0 = *reinterpret_cast<f32x4*>(red + tid * 8);
    f32x4 s1 = *reinterpret_cast<f32x4*>(red + tid * 8 + 4);
    f32x4 s = s0 + s1;
    *reinterpret_cast<f32x4*>(em2 + ((size_t)(b * Tn + t0 + tid) * 2 + ny) * 4) = s;
  }
}

// byte-map composition c(k) = a(b(k))
__device__ __forceinline__ unsigned int compose_map(unsigned int a, unsigned int b) {
#if __has_builtin(__builtin_amdgcn_perm)
  return __builtin_amdgcn_perm(a, a, b);
#else
  unsigned int c = 0;
  #pragma unroll
  for (int k = 0; k < 4; ++k) {
    unsigned int sel = (b >> (8 * k)) & 0xffu;
    c |= ((a >> (8 * sel)) & 0xffu) << (8 * k);
  }
  return c;
#endif
}

template <int J>
__device__ __forceinline__ float qb(float v) {
  return __int_as_float(__builtin_amdgcn_update_dpp(
      0, __float_as_int(v), (J * 0x55), 0xf, 0xf, true));
}

#define PSTEP(EV, T)                                                       \
  {                                                                        \
    shf[((T) - 1) * 4 + kk] = s;                                           \
    float c0 = qb<0>(s) + trc0;                                            \
    float c1 = qb<1>(s) + trc1;                                            \
    float c2 = qb<2>(s) + trc2;                                            \
    float c3 = qb<3>(s) + trc3;                                            \
    s = fmaxf(fmaxf(c0, c1), fmaxf(c2, c3)) + (EV);                        \
  }

__global__ __launch_bounds__(64) void viterbi_k(const float* __restrict__ em2,
    const float* __restrict__ lin_b, const float* __restrict__ cstart,
    const float* __restrict__ cend, const float* __restrict__ ctrans,
    int* __restrict__ out) {
  __shared__ float4 se[Tn];
  __shared__ float4 sh[Tn - 1];
  __shared__ int s_last;
  const int b = blockIdx.x, lane = threadIdx.x;
  const float4* e2 = reinterpret_cast<const float4*>(em2 + (size_t)b * Tn * 8);
  const float lb0 = lin_b[0], lb1 = lin_b[1], lb2 = lin_b[2], lb3 = lin_b[3];
  for (int i = lane; i < Tn; i += 64) {
    float4 a = e2[i * 2], c = e2[i * 2 + 1];
    se[i] = make_float4(a.x + c.x + lb0, a.y + c.y + lb1,
                        a.z + c.z + lb2, a.w + c.w + lb3);
  }
  float tr[4][4];
  #pragma unroll
  for (int j = 0; j < 4; ++j)
    #pragma unroll
    for (int k = 0; k < 4; ++k) tr[j][k] = ctrans[j * 4 + k];
  __syncthreads();

  if (lane < 4) {
    const int kk = lane;
    const float* sef = reinterpret_cast<const float*>(se);
    float* shf = reinterpret_cast<float*>(sh);
    const float trc0 = ctrans[0 * 4 + kk];
    const float trc1 = ctrans[1 * 4 + kk];
    const float trc2 = ctrans[2 * 4 + kk];
    const float trc3 = ctrans[3 * 4 + kk];
    float s = cstart[kk] + sef[kk];
    float e[8];
    #pragma unroll
    for (int d = 0; d < 8; ++d) e[d] = sef[(1 + d) * 4 + kk];
    int t = 1;
    #pragma unroll 1
    for (int g = 0; g < 127; ++g, t += 8) {
      float f[8];
      #pragma unroll
      for (int d = 0; d < 8; ++d) f[d] = e[d];
      #pragma unroll
      for (int d = 0; d < 8; ++d) e[d] = sef[(t + 8 + d) * 4 + kk];
      PSTEP(f[0], t);     PSTEP(f[1], t + 1);
      PSTEP(f[2], t + 2); PSTEP(f[3], t + 3);
      PSTEP(f[4], t + 4); PSTEP(f[5], t + 5);
      PSTEP(f[6], t + 6); PSTEP(f[7], t + 7);
    }
    PSTEP(e[0], 1017); PSTEP(e[1], 1018); PSTEP(e[2], 1019);
    PSTEP(e[3], 1020); PSTEP(e[4], 1021); PSTEP(e[5], 1022);
    PSTEP(e[6], 1023);
    s += cend[kk];
    float f0 = __shfl(s, 0), f1 = __shfl(s, 1);
    float f2 = __shfl(s, 2), f3 = __shfl(s, 3);
    if (kk == 0) {
      int tag = 0; float bf = f0;
      if (f1 > bf) { bf = f1; tag = 1; }
      if (f2 > bf) { bf = f2; tag = 2; }
      if (f3 > bf) { bf = f3; tag = 3; }
      s_last = tag;
    }
  }
  __syncthreads();

  const unsigned int ID = 0x03020100u;
  unsigned int mloc[16];
  const int t0 = lane * 16;
  #pragma unroll
  for (int k = 0; k < 16; ++k) {
    const int t = t0 + k;
    if (t < Tn - 1) {
      const float4 s = sh[t];
      const float4 e = se[t + 1];
      const float sj[4] = {s.x, s.y, s.z, s.w};
      const float ev[4] = {e.x, e.y, e.z, e.w};
      unsigned int mw = 0;
      #pragma unroll
      for (int kk = 0; kk < 4; ++kk) {
        float best = (sj[0] + tr[0][kk]) + ev[kk];
        int bi = 0;
        #pragma unroll
        for (int j = 1; j < 4; ++j) {
          float cc = (sj[j] + tr[j][kk]) + ev[kk];
          if (cc > best) { best = cc; bi = j; }
        }
        mw |= (unsigned)bi << (8 * kk);
      }
      mloc[k] = mw;
    } else {
      mloc[k] = ID;
    }
  }
  unsigned int P = mloc[15];
  #pragma unroll
  for (int k = 14; k >= 0; --k) P = compose_map(mloc[k], P);
  #pragma unroll
  for (int d = 1; d < 64; d <<= 1) {
    unsigned int q = (unsigned int)__shfl_down((int)P, d);
    if (lane + d > 63) q = ID;
    P = compose_map(P, q);
  }
  unsigned int E = (unsigned int)__shfl_down((int)P, 1);
  if (lane == 63) E = ID;
  const int last = s_last;
  unsigned int tag = (E >> (8 * last)) & 3u;
  int* ob = out + (size_t)b * Tn;
  #pragma unroll
  for (int k = 15; k >= 0; --k) {
    tag = (mloc[k] >> (8 * tag)) & 3u;
    ob[t0 + k] = (int)tag;
  }
}

extern "C" void kernel_launch(void* const* d_in, const int* in_sizes, int n_in,
                              void* d_out, int out_size, void* d_ws, size_t ws_size,
                              hipStream_t stream) {
  const float* x      = (const float*)d_in[0];
  const float* conv_w = (const float*)d_in[1];
  const float* conv_b = (const float*)d_in[2];
  const float* lin_w  = (const float*)d_in[3];
  const float* lin_b  = (const float*)d_in[4];
  const float* cstart = (const float*)d_in[5];
  const float* cend   = (const float*)d_in[6];
  const float* ctrans = (const float*)d_in[7];
  int* out = (int*)d_out;

  unsigned short* Bp = (unsigned short*)d_ws;              // 786,432 B
  float* em2 = (float*)((char*)d_ws + 786432);             // 2 MB partials
  unsigned char* xs = (unsigned char*)d_ws + 786432 + 2097152;
  const size_t xs_bytes = (size_t)Bn * 8 * XROWS * 128;    // 67.2 MB
  const size_t need = 786432 + 2097152 + xs_bytes;

  pack_b_k<<<192, 256, 0, stream>>>(conv_w, Bp);
  if (ws_size >= need) {
    presplit_k<<<dim3((XROWS * 8 + 255) / 256, Bn * 8), 256, 0, stream>>>(x, xs);
    emis_k<<<dim3(Tn / TT, 2, Bn), 256, 0, stream>>>(xs, Bp, conv_b, lin_w, em2);
  } else {
    emis_k13<<<dim3(Tn / TT, 2, Bn), 256, 0, stream>>>(x, Bp, conv_b, lin_w, em2);
  }
  viterbi_k<<<Bn, 64, 0, stream>>>(em2, lin_b, cstart, cend, ctrans, out);
}

// Round 16
// 127.497 us; speedup vs baseline: 1.1451x; 1.1450x over previous
//
#include <hip/hip_runtime.h>
#include <cstdint>
#include <cstddef>

typedef __attribute__((ext_vector_type(8))) short short8;
typedef __attribute__((ext_vector_type(4))) float f32x4;

constexpr int Bn = 64, Tn = 1024, Hn = 256, Kn = 4;
constexpr int TT = 64;             // T-rows per block
constexpr int AROWS = TT + 2;      // 66 staged x-rows (t0-1 .. t0+64)
constexpr int ARSTR = 144;         // A-LDS row stride bytes (hi 64 + lo 64 + 16 pad)
constexpr int ABUFSZ = AROWS * ARSTR;   // 9,504 B per buffer

// round-to-nearest-even fp32 -> bf16 bits
__device__ __forceinline__ unsigned bf16rne(float f) {
  unsigned u = __float_as_uint(f);
  return (u + 0x7fffu + ((u >> 16) & 1u)) >> 16;
}

// Pack conv_w into MFMA-B-fragment-ready hi/lo bf16 (verified since r11):
// Bp[fid(24 ks x 2 p x 16 nf)][lane(64)][j(8)], value = part_p(conv_w[n][i][dt])
// where k = ks*32 + (lane>>4)*8 + j (dt=k>>8, i=k&255), n = nf*16 + (lane&15).
__global__ __launch_bounds__(256) void pack_b_k(const float* __restrict__ conv_w,
                                                unsigned short* __restrict__ Bp) {
  int gt = blockIdx.x * 256 + threadIdx.x;
  int fid = gt >> 6, l = gt & 63;
  int ks = fid >> 5, rem = fid & 31;
  int p = rem >> 4, nf = rem & 15;
  int n = nf * 16 + (l & 15);
  int k0 = ks * 32 + ((l >> 4) << 3);
  short8 s;
  #pragma unroll
  for (int j = 0; j < 8; ++j) {
    int k = k0 + j;
    int dt = k >> 8, i = k & 255;
    float w = conv_w[n * 768 + i * 3 + dt];
    unsigned hb = bf16rne(w);
    if (p == 0) s[j] = (short)hb;
    else        s[j] = (short)bf16rne(w - __uint_as_float(hb << 16));
  }
  *reinterpret_cast<short8*>(Bp + (size_t)fid * 512 + l * 8) = s;
}

// lgkm-only barrier: ds_writes visible, global VGPR loads keep flying.
#define GBAR() asm volatile("s_waitcnt lgkmcnt(0)\n\ts_barrier" ::: "memory")

// Fused conv1d(k=3,pad=1)+bias+ReLU+Linear(256->4) via bf16 3-way-split MFMA
// (AhBh + AlBh + AhBl; dropped AlBl <= 2^-18 relative).
// Block: 64(T) x 128(N), 4 waves (32x64 each = 2x4 16x16 frags, acc=32).
// A: hi/lo bf16, double-buffered LDS (2 x 9,504 B), 8 groups of 32 chans.
// B: Bh double-set VGPR prefetch across STEPs; Bl SINGLE-set loaded at STEP
//    top, consumed in phase 2 (~300+ cyc later, L2 covered).
// Per-acc FP order: +AhBh, +AlBh, +AhBl (bitwise = rounds 11-13).
__global__ __launch_bounds__(256, 2) void emis_k(const float* __restrict__ x,
    const unsigned short* __restrict__ Bp, const float* __restrict__ conv_b,
    const float* __restrict__ lin_w, float* __restrict__ em2) {
  __shared__ __align__(16) char A_lds[2 * ABUFSZ];   // 19,008 B

  const int b = blockIdx.z, ny = blockIdx.y, t0 = blockIdx.x * TT;
  const int tid = threadIdx.x, lane = tid & 63, w = tid >> 6;
  const int wm = w >> 1, wn = w & 1;
  const float* xb = x + (size_t)b * Tn * Hn;

  float4 pre[3];                    // A-prefetch regs (12 VGPR)

  // issue group ig's global loads (66 rows x 8 float4 = 528 chunks)
  auto loadA = [&](int ig) {
    #pragma unroll
    for (int it = 0; it < 3; ++it) {
      int idx = it * 256 + tid;
      if (idx < AROWS * 8) {
        int row = idx >> 3, c4 = idx & 7;
        int trow = t0 - 1 + row;
        float4 v = make_float4(0.f, 0.f, 0.f, 0.f);
        if (trow >= 0 && trow < Tn)
          v = *reinterpret_cast<const float4*>(xb + (size_t)trow * Hn + ig * 32 + c4 * 4);
        pre[it] = v;
      }
    }
  };
  // convert + write pre[] into buffer at byte offset boff
  auto writeA = [&](int boff) {
    #pragma unroll
    for (int it = 0; it < 3; ++it) {
      int idx = it * 256 + tid;
      if (idx < AROWS * 8) {
        int row = idx >> 3, c4 = idx & 7;
        float vf[4] = {pre[it].x, pre[it].y, pre[it].z, pre[it].w};
        unsigned h[4], lo[4];
        #pragma unroll
        for (int q = 0; q < 4; ++q) {
          h[q] = bf16rne(vf[q]);
          lo[q] = bf16rne(vf[q] - __uint_as_float(h[q] << 16));
        }
        uint2 hp, lp;
        hp.x = h[0] | (h[1] << 16);  hp.y = h[2] | (h[3] << 16);
        lp.x = lo[0] | (lo[1] << 16); lp.y = lo[2] | (lo[3] << 16);
        char* base = A_lds + boff + row * ARSTR + c4 * 8;
        *reinterpret_cast<uint2*>(base) = hp;        // hi plane
        *reinterpret_cast<uint2*>(base + 64) = lp;   // lo plane
      }
    }
  };

  // B-fragment source base for this wave (4 nf frags per set)
  const char* bsrc = reinterpret_cast<const char*>(Bp)
      + (size_t)(ny * 8 + wn * 4) * 1024 + lane * 16;
  auto loadB4 = [&](short8* Bv, int ks, int p) {
    #pragma unroll
    for (int nf = 0; nf < 4; ++nf)
      Bv[nf] = *reinterpret_cast<const short8*>(
          bsrc + (size_t)((ks * 2 + p) * 16 + nf) * 1024);
  };

  f32x4 acc[2][4];
  #pragma unroll
  for (int mf = 0; mf < 2; ++mf)
    #pragma unroll
    for (int nf = 0; nf < 4; ++nf) acc[mf][nf] = (f32x4)0.f;

  // per-lane A base: row=(lane&15)+wm*32, k-chans=(lane>>4)*8 (16B)
  const char* aB = A_lds + (lane & 15) * ARSTR + ((lane >> 4) << 4) + wm * 32 * ARSTR;

  short8 BhA[4], BhB[4], Bl[4];

// one K-step in buffer ABUF: consume BH (prefetched) + Bl (loaded here,
// used in phase 2); prefetch next Bh set into NBH.
#define STEP(ABUF, DT, BH, NBH, KSC, KSN)                                     \
  {                                                                           \
    loadB4(Bl, (KSC), 1);                                                     \
    loadB4(NBH, (KSN), 0);                                                    \
    __builtin_amdgcn_s_setprio(1);                                            \
    _Pragma("unroll")                                                         \
    for (int mf = 0; mf < 2; ++mf) {                                          \
      const char* ap = aB + (ABUF) + (mf * 16 + (DT)) * ARSTR;                \
      short8 Ah = *reinterpret_cast<const short8*>(ap);                       \
      short8 Al = *reinterpret_cast<const short8*>(ap + 64);                  \
      _Pragma("unroll")                                                       \
      for (int nf = 0; nf < 4; ++nf) {                                        \
        f32x4 c = acc[mf][nf];                                                \
        c = __builtin_amdgcn_mfma_f32_16x16x32_bf16(Ah, BH[nf], c, 0, 0, 0);  \
        c = __builtin_amdgcn_mfma_f32_16x16x32_bf16(Al, BH[nf], c, 0, 0, 0);  \
        acc[mf][nf] = c;                                                      \
      }                                                                       \
    }                                                                         \
    _Pragma("unroll")                                                         \
    for (int mf = 0; mf < 2; ++mf) {                                          \
      const char* ap = aB + (ABUF) + (mf * 16 + (DT)) * ARSTR;                \
      short8 Ah = *reinterpret_cast<const short8*>(ap);                       \
      _Pragma("unroll")                                                       \
      for (int nf = 0; nf < 4; ++nf)                                          \
        acc[mf][nf] = __builtin_amdgcn_mfma_f32_16x16x32_bf16(                \
            Ah, Bl[nf], acc[mf][nf], 0, 0, 0);                                \
    }                                                                         \
    __builtin_amdgcn_s_setprio(0);                                            \
  }

  // prologue: A group 0 -> buf0 (latency exposed once), Bh ks=0 in flight
  loadA(0);
  loadB4(BhA, 0, 0);
  writeA(0);
  GBAR();

  #pragma unroll 1
  for (int igp = 0; igp < 4; ++igp) {
    const int ig0 = igp * 2, ig1 = ig0 + 1;
    // ---- group ig0 in buf0 ----
    loadA(ig1);                                  // issue-early for buf1
    STEP(0, 0, BhA, BhB, ig0,      8 + ig0);
    STEP(0, 1, BhB, BhA, 8 + ig0,  16 + ig0);
    STEP(0, 2, BhA, BhB, 16 + ig0, ig1);
    writeA(ABUFSZ);                              // write-late into buf1
    GBAR();
    // ---- group ig1 in buf1 ----
    if (ig1 < 7) loadA(ig1 + 1);
    STEP(ABUFSZ, 0, BhB, BhA, ig1,      8 + ig1);
    STEP(ABUFSZ, 1, BhA, BhB, 8 + ig1,  16 + ig1);
    STEP(ABUFSZ, 2, BhB, BhA, 16 + ig1, (ig1 < 7 ? ig1 + 1 : 0));
    if (ig1 < 7) writeA(0);
    GBAR();
  }
#undef STEP

  // ---- Epilogue: +conv_b, ReLU, x lin_w^T partials over this wave's cols ----
  // C/D layout: col = lane&15, row = (lane>>4)*4 + v  (m89-verified).
  f32x4 pem[2][4];   // [mf][v] -> 4 kk partial sums
  #pragma unroll
  for (int mf = 0; mf < 2; ++mf)
    #pragma unroll
    for (int v = 0; v < 4; ++v) pem[mf][v] = (f32x4)0.f;

  #pragma unroll
  for (int nf = 0; nf < 4; ++nf) {
    const int gcol = ny * 128 + wn * 64 + nf * 16 + (lane & 15);
    const float cb = conv_b[gcol];
    f32x4 lw;
    lw[0] = lin_w[gcol]; lw[1] = lin_w[256 + gcol];
    lw[2] = lin_w[512 + gcol]; lw[3] = lin_w[768 + gcol];
    #pragma unroll
    for (int mf = 0; mf < 2; ++mf)
      #pragma unroll
      for (int v = 0; v < 4; ++v) {
        float val = fmaxf(acc[mf][nf][v] + cb, 0.f);
        pem[mf][v] += val * lw;
      }
  }
  // reduce over the 16 col-lanes (lane bits 0..3)
  #pragma unroll
  for (int mf = 0; mf < 2; ++mf)
    #pragma unroll
    for (int v = 0; v < 4; ++v) {
      f32x4 t = pem[mf][v];
      #pragma unroll
      for (int m = 1; m < 16; m <<= 1) {
        f32x4 q;
        q[0] = __shfl_xor(t[0], m); q[1] = __shfl_xor(t[1], m);
        q[2] = __shfl_xor(t[2], m); q[3] = __shfl_xor(t[3], m);
        t += q;
      }
      pem[mf][v] = t;
    }
  __syncthreads();                    // all waves done with A_lds (reuse)
  // cross-wave (wn) combine via LDS: red[64 rows][2 wn][4 kk]
  float* red = reinterpret_cast<float*>(A_lds);
  if ((lane & 15) == 0) {
    const int g = lane >> 4;
    #pragma unroll
    for (int mf = 0; mf < 2; ++mf)
      #pragma unroll
      for (int v = 0; v < 4; ++v) {
        int r = wm * 32 + mf * 16 + g * 4 + v;
        *reinterpret_cast<f32x4*>(red + (r * 2 + wn) * 4) = pem[mf][v];
      }
  }
  __syncthreads();
  if (tid < TT) {
    f32x4 s0 = *reinterpret_cast<f32x4*>(red + tid * 8);
    f32x4 s1 = *reinterpret_cast<f32x4*>(red + tid * 8 + 4);
    f32x4 s = s0 + s1;
    *reinterpret_cast<f32x4*>(em2 + ((size_t)(b * Tn + t0 + tid) * 2 + ny) * 4) = s;
  }
}

// byte-map composition c(k) = a(b(k))
__device__ __forceinline__ unsigned int compose_map(unsigned int a, unsigned int b) {
#if __has_builtin(__builtin_amdgcn_perm)
  return __builtin_amdgcn_perm(a, a, b);
#else
  unsigned int c = 0;
  #pragma unroll
  for (int k = 0; k < 4; ++k) {
    unsigned int sel = (b >> (8 * k)) & 0xffu;
    c |= ((a >> (8 * sel)) & 0xffu) << (8 * k);
  }
  return c;
#endif
}

// quad_perm broadcast of lane J (within each 4-lane quad) via DPP
template <int J>
__device__ __forceinline__ float qb(float v) {
  return __int_as_float(__builtin_amdgcn_update_dpp(
      0, __float_as_int(v), (J * 0x55), 0xf, 0xf, true));
}

// One quad-parallel Viterbi step for lane k (values bitwise = scalar form).
#define PSTEP(EV, T)                                                       \
  {                                                                        \
    shf[((T) - 1) * 4 + kk] = s;                                           \
    float c0 = qb<0>(s) + trc0;                                            \
    float c1 = qb<1>(s) + trc1;                                            \
    float c2 = qb<2>(s) + trc2;                                            \
    float c3 = qb<3>(s) + trc3;                                            \
    s = fmaxf(fmaxf(c0, c1), fmaxf(c2, c3)) + (EV);                        \
  }

// CRF Viterbi decode. Stage: se[t] = em2[t][half0] + em2[t][half1] + lin_b.
// Forward: 4-lane quad-parallel scan. Backtrace: 64 lanes rebuild argmax
// maps, v_perm suffix-scan (integer-exact).
__global__ __launch_bounds__(64) void viterbi_k(const float* __restrict__ em2,
    const float* __restrict__ lin_b, const float* __restrict__ cstart,
    const float* __restrict__ cend, const float* __restrict__ ctrans,
    int* __restrict__ out) {
  __shared__ float4 se[Tn];          // emissions, 16 KB
  __shared__ float4 sh[Tn - 1];      // score vector BEFORE step t+1, 16 KB
  __shared__ int s_last;
  const int b = blockIdx.x, lane = threadIdx.x;
  const float4* e2 = reinterpret_cast<const float4*>(em2 + (size_t)b * Tn * 8);
  const float lb0 = lin_b[0], lb1 = lin_b[1], lb2 = lin_b[2], lb3 = lin_b[3];
  for (int i = lane; i < Tn; i += 64) {
    float4 a = e2[i * 2], c = e2[i * 2 + 1];
    se[i] = make_float4(a.x + c.x + lb0, a.y + c.y + lb1,
                        a.z + c.z + lb2, a.w + c.w + lb3);
  }
  float tr[4][4];
  #pragma unroll
  for (int j = 0; j < 4; ++j)
    #pragma unroll
    for (int k = 0; k < 4; ++k) tr[j][k] = ctrans[j * 4 + k];
  __syncthreads();

  if (lane < 4) {
    const int kk = lane;
    const float* sef = reinterpret_cast<const float*>(se);
    float* shf = reinterpret_cast<float*>(sh);
    const float trc0 = ctrans[0 * 4 + kk];
    const float trc1 = ctrans[1 * 4 + kk];
    const float trc2 = ctrans[2 * 4 + kk];
    const float trc3 = ctrans[3 * 4 + kk];
    float s = cstart[kk] + sef[kk];
    float e[8];
    #pragma unroll
    for (int d = 0; d < 8; ++d) e[d] = sef[(1 + d) * 4 + kk];
    int t = 1;
    #pragma unroll 1
    for (int g = 0; g < 127; ++g, t += 8) {   // t = 1..1016
      float f[8];
      #pragma unroll
      for (int d = 0; d < 8; ++d) f[d] = e[d];
      #pragma unroll
      for (int d = 0; d < 8; ++d) e[d] = sef[(t + 8 + d) * 4 + kk];
      PSTEP(f[0], t);     PSTEP(f[1], t + 1);
      PSTEP(f[2], t + 2); PSTEP(f[3], t + 3);
      PSTEP(f[4], t + 4); PSTEP(f[5], t + 5);
      PSTEP(f[6], t + 6); PSTEP(f[7], t + 7);
    }
    PSTEP(e[0], 1017); PSTEP(e[1], 1018); PSTEP(e[2], 1019);
    PSTEP(e[3], 1020); PSTEP(e[4], 1021); PSTEP(e[5], 1022);
    PSTEP(e[6], 1023);
    s += cend[kk];
    float f0 = __shfl(s, 0), f1 = __shfl(s, 1);
    float f2 = __shfl(s, 2), f3 = __shfl(s, 3);
    if (kk == 0) {
      int tag = 0; float bf = f0;
      if (f1 > bf) { bf = f1; tag = 1; }
      if (f2 > bf) { bf = f2; tag = 2; }
      if (f3 > bf) { bf = f3; tag = 3; }
      s_last = tag;
    }
  }
  __syncthreads();

  const unsigned int ID = 0x03020100u;
  unsigned int mloc[16];
  const int t0 = lane * 16;
  #pragma unroll
  for (int k = 0; k < 16; ++k) {
    const int t = t0 + k;
    if (t < Tn - 1) {
      const float4 s = sh[t];
      const float4 e = se[t + 1];
      const float sj[4] = {s.x, s.y, s.z, s.w};
      const float ev[4] = {e.x, e.y, e.z, e.w};
      unsigned int mw = 0;
      #pragma unroll
      for (int kk = 0; kk < 4; ++kk) {
        float best = (sj[0] + tr[0][kk]) + ev[kk];
        int bi = 0;
        #pragma unroll
        for (int j = 1; j < 4; ++j) {
          float cc = (sj[j] + tr[j][kk]) + ev[kk];
          if (cc > best) { best = cc; bi = j; }
        }
        mw |= (unsigned)bi << (8 * kk);
      }
      mloc[k] = mw;
    } else {
      mloc[k] = ID;
    }
  }
  unsigned int P = mloc[15];
  #pragma unroll
  for (int k = 14; k >= 0; --k) P = compose_map(mloc[k], P);
  #pragma unroll
  for (int d = 1; d < 64; d <<= 1) {
    unsigned int q = (unsigned int)__shfl_down((int)P, d);
    if (lane + d > 63) q = ID;
    P = compose_map(P, q);
  }
  unsigned int E = (unsigned int)__shfl_down((int)P, 1);
  if (lane == 63) E = ID;
  const int last = s_last;
  unsigned int tag = (E >> (8 * last)) & 3u;
  int* ob = out + (size_t)b * Tn;
  #pragma unroll
  for (int k = 15; k >= 0; --k) {
    tag = (mloc[k] >> (8 * tag)) & 3u;
    ob[t0 + k] = (int)tag;
  }
}

extern "C" void kernel_launch(void* const* d_in, const int* in_sizes, int n_in,
                              void* d_out, int out_size, void* d_ws, size_t ws_size,
                              hipStream_t stream) {
  const float* x      = (const float*)d_in[0];
  const float* conv_w = (const float*)d_in[1];
  const float* conv_b = (const float*)d_in[2];
  const float* lin_w  = (const float*)d_in[3];
  const float* lin_b  = (const float*)d_in[4];
  const float* cstart = (const float*)d_in[5];
  const float* cend   = (const float*)d_in[6];
  const float* ctrans = (const float*)d_in[7];
  int* out = (int*)d_out;

  unsigned short* Bp = (unsigned short*)d_ws;              // 786,432 B
  float* em2 = (float*)((char*)d_ws + 786432);             // 2 MB partials

  pack_b_k<<<192, 256, 0, stream>>>(conv_w, Bp);
  emis_k<<<dim3(Tn / TT, 2, Bn), 256, 0, stream>>>(x, Bp, conv_b, lin_w, em2);
  viterbi_k<<<Bn, 64, 0, stream>>>(em2, lin_b, cstart, cend, ctrans, out);
}

// Round 17
// 123.674 us; speedup vs baseline: 1.1805x; 1.0309x over previous
//
#include <hip/hip_runtime.h>
#include <cstdint>
#include <cstddef>

typedef __attribute__((ext_vector_type(8))) short short8;
typedef __attribute__((ext_vector_type(4))) float f32x4;

constexpr int Bn = 64, Tn = 1024, Hn = 256, Kn = 4;
constexpr int TT = 64;             // T-rows per block
constexpr int AROWS = TT + 2;      // 66 staged x-rows (t0-1 .. t0+64)
constexpr int ARSTR = 144;         // A-LDS row stride bytes (hi 64 + lo 64 + 16 pad)
constexpr int ABUFSZ = AROWS * ARSTR;   // 9,504 B per buffer

// round-to-nearest-even fp32 -> bf16 bits
__device__ __forceinline__ unsigned bf16rne(float f) {
  unsigned u = __float_as_uint(f);
  return (u + 0x7fffu + ((u >> 16) & 1u)) >> 16;
}

// Pack conv_w into MFMA-B-fragment-ready hi/lo bf16 (verified since r11):
// Bp[fid(24 ks x 2 p x 16 nf)][lane(64)][j(8)], value = part_p(conv_w[n][i][dt])
// where k = ks*32 + (lane>>4)*8 + j (dt=k>>8, i=k&255), n = nf*16 + (lane&15).
__global__ __launch_bounds__(256) void pack_b_k(const float* __restrict__ conv_w,
                                                unsigned short* __restrict__ Bp) {
  int gt = blockIdx.x * 256 + threadIdx.x;
  int fid = gt >> 6, l = gt & 63;
  int ks = fid >> 5, rem = fid & 31;
  int p = rem >> 4, nf = rem & 15;
  int n = nf * 16 + (l & 15);
  int k0 = ks * 32 + ((l >> 4) << 3);
  short8 s;
  #pragma unroll
  for (int j = 0; j < 8; ++j) {
    int k = k0 + j;
    int dt = k >> 8, i = k & 255;
    float w = conv_w[n * 768 + i * 3 + dt];
    unsigned hb = bf16rne(w);
    if (p == 0) s[j] = (short)hb;
    else        s[j] = (short)bf16rne(w - __uint_as_float(hb << 16));
  }
  *reinterpret_cast<short8*>(Bp + (size_t)fid * 512 + l * 8) = s;
}

// lgkm-only barrier: ds_writes visible, global VGPR loads keep flying.
#define GBAR() asm volatile("s_waitcnt lgkmcnt(0)\n\ts_barrier" ::: "memory")

// Fused conv1d(k=3,pad=1)+bias+ReLU+Linear(256->4) via bf16 3-way-split MFMA
// (AhBh + AlBh + AhBl; dropped AlBl <= 2^-18 relative).
// Block: 64(T) x 128(N), 4 waves (32x64 each = 2x4 16x16 frags, acc=32).
// A: hi/lo bf16, double-buffered LDS (2 x 9,504 B), 8 groups of 32 chans.
// B: Bh AND Bl double-set VGPR prefetch, issued one FULL step (~350 cyc)
//    before consumption -> L2 latency fully covered (round-13 pipeline,
//    round-16 tile).
// Per-acc FP order: +AhBh, +AlBh, +AhBl (bitwise = rounds 11-16).
__global__ __launch_bounds__(256, 2) void emis_k(const float* __restrict__ x,
    const unsigned short* __restrict__ Bp, const float* __restrict__ conv_b,
    const float* __restrict__ lin_w, float* __restrict__ em2) {
  __shared__ __align__(16) char A_lds[2 * ABUFSZ];   // 19,008 B

  const int b = blockIdx.z, ny = blockIdx.y, t0 = blockIdx.x * TT;
  const int tid = threadIdx.x, lane = tid & 63, w = tid >> 6;
  const int wm = w >> 1, wn = w & 1;
  const float* xb = x + (size_t)b * Tn * Hn;

  float4 pre[3];                    // A-prefetch regs (12 VGPR)

  // issue group ig's global loads (66 rows x 8 float4 = 528 chunks)
  auto loadA = [&](int ig) {
    #pragma unroll
    for (int it = 0; it < 3; ++it) {
      int idx = it * 256 + tid;
      if (idx < AROWS * 8) {
        int row = idx >> 3, c4 = idx & 7;
        int trow = t0 - 1 + row;
        float4 v = make_float4(0.f, 0.f, 0.f, 0.f);
        if (trow >= 0 && trow < Tn)
          v = *reinterpret_cast<const float4*>(xb + (size_t)trow * Hn + ig * 32 + c4 * 4);
        pre[it] = v;
      }
    }
  };
  // convert + write pre[] into buffer at byte offset boff
  auto writeA = [&](int boff) {
    #pragma unroll
    for (int it = 0; it < 3; ++it) {
      int idx = it * 256 + tid;
      if (idx < AROWS * 8) {
        int row = idx >> 3, c4 = idx & 7;
        float vf[4] = {pre[it].x, pre[it].y, pre[it].z, pre[it].w};
        unsigned h[4], lo[4];
        #pragma unroll
        for (int q = 0; q < 4; ++q) {
          h[q] = bf16rne(vf[q]);
          lo[q] = bf16rne(vf[q] - __uint_as_float(h[q] << 16));
        }
        uint2 hp, lp;
        hp.x = h[0] | (h[1] << 16);  hp.y = h[2] | (h[3] << 16);
        lp.x = lo[0] | (lo[1] << 16); lp.y = lo[2] | (lo[3] << 16);
        char* base = A_lds + boff + row * ARSTR + c4 * 8;
        *reinterpret_cast<uint2*>(base) = hp;        // hi plane
        *reinterpret_cast<uint2*>(base + 64) = lp;   // lo plane
      }
    }
  };

  // B-fragment source base for this wave (4 nf x 2 p frags per step)
  const char* bsrc = reinterpret_cast<const char*>(Bp)
      + (size_t)(ny * 8 + wn * 4) * 1024 + lane * 16;
  auto loadB = [&](short8* Bh, short8* Bl, int ks) {
    #pragma unroll
    for (int nf = 0; nf < 4; ++nf) {
      Bh[nf] = *reinterpret_cast<const short8*>(bsrc + (size_t)((ks * 2 + 0) * 16 + nf) * 1024);
      Bl[nf] = *reinterpret_cast<const short8*>(bsrc + (size_t)((ks * 2 + 1) * 16 + nf) * 1024);
    }
  };

  f32x4 acc[2][4];
  #pragma unroll
  for (int mf = 0; mf < 2; ++mf)
    #pragma unroll
    for (int nf = 0; nf < 4; ++nf) acc[mf][nf] = (f32x4)0.f;

  // per-lane A base: row=(lane&15)+wm*32, k-chans=(lane>>4)*8 (16B)
  const char* aB = A_lds + (lane & 15) * ARSTR + ((lane >> 4) << 4) + wm * 32 * ARSTR;

  short8 BhA[4], BlA[4], BhB[4], BlB[4];

// one K-step in buffer ABUF: consume (BH,BL) prefetched last step;
// prefetch next step's set into (NBH,NBL).
#define STEP(ABUF, DT, BH, BL, NBH, NBL, KSN)                                 \
  {                                                                           \
    loadB(NBH, NBL, (KSN));                                                   \
    __builtin_amdgcn_s_setprio(1);                                            \
    _Pragma("unroll")                                                         \
    for (int mf = 0; mf < 2; ++mf) {                                          \
      const char* ap = aB + (ABUF) + (mf * 16 + (DT)) * ARSTR;                \
      short8 Ah = *reinterpret_cast<const short8*>(ap);                       \
      short8 Al = *reinterpret_cast<const short8*>(ap + 64);                  \
      _Pragma("unroll")                                                       \
      for (int nf = 0; nf < 4; ++nf) {                                        \
        f32x4 c = acc[mf][nf];                                                \
        c = __builtin_amdgcn_mfma_f32_16x16x32_bf16(Ah, BH[nf], c, 0, 0, 0);  \
        c = __builtin_amdgcn_mfma_f32_16x16x32_bf16(Al, BH[nf], c, 0, 0, 0);  \
        c = __builtin_amdgcn_mfma_f32_16x16x32_bf16(Ah, BL[nf], c, 0, 0, 0);  \
        acc[mf][nf] = c;                                                      \
      }                                                                       \
    }                                                                         \
    __builtin_amdgcn_s_setprio(0);                                            \
  }

  // prologue: A group 0 -> buf0 (latency exposed once), B ks=0 in flight
  loadA(0);
  loadB(BhA, BlA, 0);
  writeA(0);
  GBAR();

  #pragma unroll 1
  for (int igp = 0; igp < 4; ++igp) {
    const int ig0 = igp * 2, ig1 = ig0 + 1;
    // ---- group ig0 in buf0 (consumes sets A,B,A) ----
    loadA(ig1);                                  // issue-early for buf1
    STEP(0, 0, BhA, BlA, BhB, BlB, 8 + ig0);
    STEP(0, 1, BhB, BlB, BhA, BlA, 16 + ig0);
    STEP(0, 2, BhA, BlA, BhB, BlB, ig1);
    writeA(ABUFSZ);                              // write-late into buf1
    GBAR();
    // ---- group ig1 in buf1 (consumes sets B,A,B) ----
    if (ig1 < 7) loadA(ig1 + 1);
    STEP(ABUFSZ, 0, BhB, BlB, BhA, BlA, 8 + ig1);
    STEP(ABUFSZ, 1, BhA, BlA, BhB, BlB, 16 + ig1);
    STEP(ABUFSZ, 2, BhB, BlB, BhA, BlA, (ig1 < 7 ? ig1 + 1 : 0));
    if (ig1 < 7) writeA(0);
    GBAR();
  }
#undef STEP

  // ---- Epilogue: +conv_b, ReLU, x lin_w^T partials over this wave's cols ----
  // C/D layout: col = lane&15, row = (lane>>4)*4 + v  (m89-verified).
  f32x4 pem[2][4];   // [mf][v] -> 4 kk partial sums
  #pragma unroll
  for (int mf = 0; mf < 2; ++mf)
    #pragma unroll
    for (int v = 0; v < 4; ++v) pem[mf][v] = (f32x4)0.f;

  #pragma unroll
  for (int nf = 0; nf < 4; ++nf) {
    const int gcol = ny * 128 + wn * 64 + nf * 16 + (lane & 15);
    const float cb = conv_b[gcol];
    f32x4 lw;
    lw[0] = lin_w[gcol]; lw[1] = lin_w[256 + gcol];
    lw[2] = lin_w[512 + gcol]; lw[3] = lin_w[768 + gcol];
    #pragma unroll
    for (int mf = 0; mf < 2; ++mf)
      #pragma unroll
      for (int v = 0; v < 4; ++v) {
        float val = fmaxf(acc[mf][nf][v] + cb, 0.f);
        pem[mf][v] += val * lw;
      }
  }
  // reduce over the 16 col-lanes (lane bits 0..3)
  #pragma unroll
  for (int mf = 0; mf < 2; ++mf)
    #pragma unroll
    for (int v = 0; v < 4; ++v) {
      f32x4 t = pem[mf][v];
      #pragma unroll
      for (int m = 1; m < 16; m <<= 1) {
        f32x4 q;
        q[0] = __shfl_xor(t[0], m); q[1] = __shfl_xor(t[1], m);
        q[2] = __shfl_xor(t[2], m); q[3] = __shfl_xor(t[3], m);
        t += q;
      }
      pem[mf][v] = t;
    }
  __syncthreads();                    // all waves done with A_lds (reuse)
  // cross-wave (wn) combine via LDS: red[64 rows][2 wn][4 kk]
  float* red = reinterpret_cast<float*>(A_lds);
  if ((lane & 15) == 0) {
    const int g = lane >> 4;
    #pragma unroll
    for (int mf = 0; mf < 2; ++mf)
      #pragma unroll
      for (int v = 0; v < 4; ++v) {
        int r = wm * 32 + mf * 16 + g * 4 + v;
        *reinterpret_cast<f32x4*>(red + (r * 2 + wn) * 4) = pem[mf][v];
      }
  }
  __syncthreads();
  if (tid < TT) {
    f32x4 s0 = *reinterpret_cast<f32x4*>(red + tid * 8);
    f32x4 s1 = *reinterpret_cast<f32x4*>(red + tid * 8 + 4);
    f32x4 s = s0 + s1;
    *reinterpret_cast<f32x4*>(em2 + ((size_t)(b * Tn + t0 + tid) * 2 + ny) * 4) = s;
  }
}

// byte-map composition c(k) = a(b(k))
__device__ __forceinline__ unsigned int compose_map(unsigned int a, unsigned int b) {
#if __has_builtin(__builtin_amdgcn_perm)
  return __builtin_amdgcn_perm(a, a, b);
#else
  unsigned int c = 0;
  #pragma unroll
  for (int k = 0; k < 4; ++k) {
    unsigned int sel = (b >> (8 * k)) & 0xffu;
    c |= ((a >> (8 * sel)) & 0xffu) << (8 * k);
  }
  return c;
#endif
}

// quad_perm broadcast of lane J (within each 4-lane quad) via DPP
template <int J>
__device__ __forceinline__ float qb(float v) {
  return __int_as_float(__builtin_amdgcn_update_dpp(
      0, __float_as_int(v), (J * 0x55), 0xf, 0xf, true));
}

// One quad-parallel Viterbi step for lane k (values bitwise = scalar form).
#define PSTEP(EV, T)                                                       \
  {                                                                        \
    shf[((T) - 1) * 4 + kk] = s;                                           \
    float c0 = qb<0>(s) + trc0;                                            \
    float c1 = qb<1>(s) + trc1;                                            \
    float c2 = qb<2>(s) + trc2;                                            \
    float c3 = qb<3>(s) + trc3;                                            \
    s = fmaxf(fmaxf(c0, c1), fmaxf(c2, c3)) + (EV);                        \
  }

// CRF Viterbi decode. Stage: se[t] = em2[t][half0] + em2[t][half1] + lin_b.
// Forward: 4-lane quad-parallel scan. Backtrace: 64 lanes rebuild argmax
// maps, v_perm suffix-scan (integer-exact).
__global__ __launch_bounds__(64) void viterbi_k(const float* __restrict__ em2,
    const float* __restrict__ lin_b, const float* __restrict__ cstart,
    const float* __restrict__ cend, const float* __restrict__ ctrans,
    int* __restrict__ out) {
  __shared__ float4 se[Tn];          // emissions, 16 KB
  __shared__ float4 sh[Tn - 1];      // score vector BEFORE step t+1, 16 KB
  __shared__ int s_last;
  const int b = blockIdx.x, lane = threadIdx.x;
  const float4* e2 = reinterpret_cast<const float4*>(em2 + (size_t)b * Tn * 8);
  const float lb0 = lin_b[0], lb1 = lin_b[1], lb2 = lin_b[2], lb3 = lin_b[3];
  for (int i = lane; i < Tn; i += 64) {
    float4 a = e2[i * 2], c = e2[i * 2 + 1];
    se[i] = make_float4(a.x + c.x + lb0, a.y + c.y + lb1,
                        a.z + c.z + lb2, a.w + c.w + lb3);
  }
  float tr[4][4];
  #pragma unroll
  for (int j = 0; j < 4; ++j)
    #pragma unroll
    for (int k = 0; k < 4; ++k) tr[j][k] = ctrans[j * 4 + k];
  __syncthreads();

  if (lane < 4) {
    const int kk = lane;
    const float* sef = reinterpret_cast<const float*>(se);
    float* shf = reinterpret_cast<float*>(sh);
    const float trc0 = ctrans[0 * 4 + kk];
    const float trc1 = ctrans[1 * 4 + kk];
    const float trc2 = ctrans[2 * 4 + kk];
    const float trc3 = ctrans[3 * 4 + kk];
    float s = cstart[kk] + sef[kk];
    float e[8];
    #pragma unroll
    for (int d = 0; d < 8; ++d) e[d] = sef[(1 + d) * 4 + kk];
    int t = 1;
    #pragma unroll 1
    for (int g = 0; g < 127; ++g, t += 8) {   // t = 1..1016
      float f[8];
      #pragma unroll
      for (int d = 0; d < 8; ++d) f[d] = e[d];
      #pragma unroll
      for (int d = 0; d < 8; ++d) e[d] = sef[(t + 8 + d) * 4 + kk];
      PSTEP(f[0], t);     PSTEP(f[1], t + 1);
      PSTEP(f[2], t + 2); PSTEP(f[3], t + 3);
      PSTEP(f[4], t + 4); PSTEP(f[5], t + 5);
      PSTEP(f[6], t + 6); PSTEP(f[7], t + 7);
    }
    PSTEP(e[0], 1017); PSTEP(e[1], 1018); PSTEP(e[2], 1019);
    PSTEP(e[3], 1020); PSTEP(e[4], 1021); PSTEP(e[5], 1022);
    PSTEP(e[6], 1023);
    s += cend[kk];
    float f0 = __shfl(s, 0), f1 = __shfl(s, 1);
    float f2 = __shfl(s, 2), f3 = __shfl(s, 3);
    if (kk == 0) {
      int tag = 0; float bf = f0;
      if (f1 > bf) { bf = f1; tag = 1; }
      if (f2 > bf) { bf = f2; tag = 2; }
      if (f3 > bf) { bf = f3; tag = 3; }
      s_last = tag;
    }
  }
  __syncthreads();

  const unsigned int ID = 0x03020100u;
  unsigned int mloc[16];
  const int t0 = lane * 16;
  #pragma unroll
  for (int k = 0; k < 16; ++k) {
    const int t = t0 + k;
    if (t < Tn - 1) {
      const float4 s = sh[t];
      const float4 e = se[t + 1];
      const float sj[4] = {s.x, s.y, s.z, s.w};
      const float ev[4] = {e.x, e.y, e.z, e.w};
      unsigned int mw = 0;
      #pragma unroll
      for (int kk = 0; kk < 4; ++kk) {
        float best = (sj[0] + tr[0][kk]) + ev[kk];
        int bi = 0;
        #pragma unroll
        for (int j = 1; j < 4; ++j) {
          float cc = (sj[j] + tr[j][kk]) + ev[kk];
          if (cc > best) { best = cc; bi = j; }
        }
        mw |= (unsigned)bi << (8 * kk);
      }
      mloc[k] = mw;
    } else {
      mloc[k] = ID;
    }
  }
  unsigned int P = mloc[15];
  #pragma unroll
  for (int k = 14; k >= 0; --k) P = compose_map(mloc[k], P);
  #pragma unroll
  for (int d = 1; d < 64; d <<= 1) {
    unsigned int q = (unsigned int)__shfl_down((int)P, d);
    if (lane + d > 63) q = ID;
    P = compose_map(P, q);
  }
  unsigned int E = (unsigned int)__shfl_down((int)P, 1);
  if (lane == 63) E = ID;
  const int last = s_last;
  unsigned int tag = (E >> (8 * last)) & 3u;
  int* ob = out + (size_t)b * Tn;
  #pragma unroll
  for (int k = 15; k >= 0; --k) {
    tag = (mloc[k] >> (8 * tag)) & 3u;
    ob[t0 + k] = (int)tag;
  }
}

extern "C" void kernel_launch(void* const* d_in, const int* in_sizes, int n_in,
                              void* d_out, int out_size, void* d_ws, size_t ws_size,
                              hipStream_t stream) {
  const float* x      = (const float*)d_in[0];
  const float* conv_w = (const float*)d_in[1];
  const float* conv_b = (const float*)d_in[2];
  const float* lin_w  = (const float*)d_in[3];
  const float* lin_b  = (const float*)d_in[4];
  const float* cstart = (const float*)d_in[5];
  const float* cend   = (const float*)d_in[6];
  const float* ctrans = (const float*)d_in[7];
  int* out = (int*)d_out;

  unsigned short* Bp = (unsigned short*)d_ws;              // 786,432 B
  float* em2 = (float*)((char*)d_ws + 786432);             // 2 MB partials

  pack_b_k<<<192, 256, 0, stream>>>(conv_w, Bp);
  emis_k<<<dim3(Tn / TT, 2, Bn), 256, 0, stream>>>(x, Bp, conv_b, lin_w, em2);
  viterbi_k<<<Bn, 64, 0, stream>>>(em2, lin_b, cstart, cend, ctrans, out);
}